// Round 7
// baseline (615.878 us; speedup 1.0000x reference)
//
#include <hip/hip_runtime.h>
#include <float.h>

#define BATCH 32
#define C_IN 16
#define C_OUT 32
#define NTOK 2048
#define KNN 3

#define RN 4                  // n-columns per thread
#define NCHUNK (256 * RN)     // 1024 n per block

// Kernel 1: transpose x (B,C,N) -> xT (B,N,C), sq[b][n] = sum_c x^2 (rounded mul, seq add)
__global__ void __launch_bounds__(256) transpose_sq_kernel(
    const float* __restrict__ x, float* __restrict__ xT, float* __restrict__ sq)
{
    const int n = blockIdx.x * 256 + threadIdx.x;
    const int b = blockIdx.y;
    const float* xb = x + (size_t)b * C_IN * NTOK;

    float v[C_IN];
#pragma unroll
    for (int c = 0; c < C_IN; ++c) v[c] = xb[(size_t)c * NTOK + n];

    float acc = 0.0f;
#pragma unroll
    for (int c = 0; c < C_IN; ++c) acc = __fadd_rn(acc, __fmul_rn(v[c], v[c]));
    sq[(size_t)b * NTOK + n] = acc;

    float4* dst = (float4*)(xT + ((size_t)b * NTOK + n) * C_IN);
#pragma unroll
    for (int j = 0; j < 4; ++j)
        dst[j] = make_float4(v[4 * j + 0], v[4 * j + 1], v[4 * j + 2], v[4 * j + 3]);
}

// Kernel 2: block = 256 threads, RN=4 n's each; scans one SEG-long m-segment
// (x-tile + sq-tile in LDS). Inner loop is at its source instruction floor
// (~29 VALU per (n,m), measured ~3 cyc/inst). This round: occupancy — SEG=64,
// Z=32 -> 8 blocks/CU; __launch_bounds__(256,8) caps VGPR at 64 = the
// compiler's natural allocation (rounds 4-6 all chose 64 under looser caps).
// Partial record compacted to 4 words: d0,d1,d2 + packed 7-bit local indices.
template<int SEG>
__global__ void __launch_bounds__(256, 8) knn_partial_kernel(
    const float* __restrict__ xT, const float* __restrict__ sq,
    float* __restrict__ part)
{
    __shared__ float lds_x[SEG * C_IN];   // SEG=64 -> 4 KB
    __shared__ float lds_sq[SEG];

    const int tid = threadIdx.x;
    const int b = blockIdx.y;
    const int z = blockIdx.z;
    const int nbase = blockIdx.x * NCHUNK;
    const int mbase = z * SEG;

    const float* xb  = xT + (size_t)b * NTOK * C_IN;
    const float* sqb = sq + (size_t)b * NTOK;

    // stage m-tile + sq-tile (coalesced float4)
    {
        const float4* gsrc = (const float4*)(xb + (size_t)mbase * C_IN);
        float4* ldst = (float4*)lds_x;
#pragma unroll
        for (int j = 0; j < SEG / 64; ++j)
            ldst[tid + 256 * j] = gsrc[tid + 256 * j];
        if (tid < SEG / 4)
            ((float4*)lds_sq)[tid] = ((const float4*)(sqb + mbase))[tid];
    }

    // own columns
    float xn[RN][C_IN];
    float sqn[RN];
#pragma unroll
    for (int q = 0; q < RN; ++q) {
        const int n = nbase + q * 256 + tid;
        const float4* src = (const float4*)(xb + (size_t)n * C_IN);
#pragma unroll
        for (int j = 0; j < 4; ++j) {
            float4 t = src[j];
            xn[q][4 * j + 0] = t.x; xn[q][4 * j + 1] = t.y;
            xn[q][4 * j + 2] = t.z; xn[q][4 * j + 3] = t.w;
        }
        sqn[q] = sqb[n];
    }
    __syncthreads();

    float d0[RN], d1[RN], d2[RN];
    int   i0[RN], i1[RN], i2[RN];
#pragma unroll
    for (int q = 0; q < RN; ++q) {
        d0[q] = FLT_MAX; d1[q] = FLT_MAX; d2[q] = FLT_MAX;
        i0[q] = 0; i1[q] = 0; i2[q] = 0;
    }

    // chunked scan: 4 m's per chunk, inner fully unrolled (immediate ds offsets)
    for (int mc = 0; mc < SEG; mc += 4) {
        const float4 sq4 = *((const float4*)(lds_sq + mc));   // broadcast b128
        const float sqm[4] = { sq4.x, sq4.y, sq4.z, sq4.w };
        const float* lxc = lds_x + mc * C_IN;

#pragma unroll
        for (int u = 0; u < 4; ++u) {
            const float4* r4 = (const float4*)(lxc + u * C_IN);
            const float4 A0 = r4[0], A1 = r4[1], A2 = r4[2], A3 = r4[3];
            const int m = mc + u;   // local index (0..SEG-1)

#pragma unroll
            for (int q = 0; q < RN; ++q) {
                // sequential c-chain, bitexact to the fp32 reference recipe
                float g = 0.0f;
                g = __fmaf_rn(xn[q][0],  A0.x, g); g = __fmaf_rn(xn[q][1],  A0.y, g);
                g = __fmaf_rn(xn[q][2],  A0.z, g); g = __fmaf_rn(xn[q][3],  A0.w, g);
                g = __fmaf_rn(xn[q][4],  A1.x, g); g = __fmaf_rn(xn[q][5],  A1.y, g);
                g = __fmaf_rn(xn[q][6],  A1.z, g); g = __fmaf_rn(xn[q][7],  A1.w, g);
                g = __fmaf_rn(xn[q][8],  A2.x, g); g = __fmaf_rn(xn[q][9],  A2.y, g);
                g = __fmaf_rn(xn[q][10], A2.z, g); g = __fmaf_rn(xn[q][11], A2.w, g);
                g = __fmaf_rn(xn[q][12], A3.x, g); g = __fmaf_rn(xn[q][13], A3.y, g);
                g = __fmaf_rn(xn[q][14], A3.z, g); g = __fmaf_rn(xn[q][15], A3.w, g);

                // (sqn - 2g) + sqm ; fma(-2,g,sqn) bitexact to sub(sqn, mul(2,g))
                const float d = __fadd_rn(__fmaf_rn(-2.0f, g, sqn[q]), sqm[u]);

                // branchless tie-exact top-3 insert (strict <: earlier index wins)
                const bool c0 = d < d0[q], c1 = d < d1[q], c2 = d < d2[q];
                const float od0 = d0[q], od1 = d1[q];
                const int   oi0 = i0[q], oi1 = i1[q];
                d0[q] = fminf(d, d0[q]);
                d1[q] = __builtin_amdgcn_fmed3f(d, od0, d1[q]);
                d2[q] = __builtin_amdgcn_fmed3f(d, od1, d2[q]);
                i0[q] = c0 ? m : i0[q];
                i1[q] = c0 ? oi0 : (c1 ? m : i1[q]);
                i2[q] = c1 ? oi1 : (c2 ? m : i2[q]);
            }
        }
    }

    // 4-word partial record: part[((w*Z + z)*BATCH + b)*NTOK + n]
    // w=0..2: d0,d1,d2 ; w=3: local indices packed 7|7|7 bits
    const size_t stride = (size_t)(NTOK / SEG) * BATCH * NTOK;
#pragma unroll
    for (int q = 0; q < RN; ++q) {
        const int n = nbase + q * 256 + tid;
        const size_t base = ((size_t)z * BATCH + b) * NTOK + n;
        const unsigned packed = (unsigned)i0[q] | ((unsigned)i1[q] << 7) | ((unsigned)i2[q] << 14);
        part[base + 0 * stride] = d0[q];
        part[base + 1 * stride] = d1[q];
        part[base + 2 * stride] = d2[q];
        part[base + 3 * stride] = __int_as_float((int)packed);
    }
}

// Kernel 3: merge Z partials per n (ascending z = ascending m-range, strict <
// keeps earlier index), gather 3 neighbor columns, conv epilogue.
template<int SEG>
__global__ void __launch_bounds__(256) merge_conv_kernel(
    const float* __restrict__ xT, const float* __restrict__ part,
    const float* __restrict__ W, const float* __restrict__ bias,
    float* __restrict__ out)
{
    constexpr int Z = NTOK / SEG;
    const int n = blockIdx.x * 256 + threadIdx.x;
    const int b = blockIdx.y;

    float D0 = FLT_MAX, D1 = FLT_MAX, D2 = FLT_MAX;
    int   I0 = 0,       I1 = 0,       I2 = 0;

    const size_t stride = (size_t)Z * BATCH * NTOK;
#pragma unroll
    for (int z = 0; z < Z; ++z) {
        const size_t base = ((size_t)z * BATCH + b) * NTOK + n;
        const float pd[KNN] = { part[base], part[base + stride], part[base + 2 * stride] };
        const unsigned packed = (unsigned)__float_as_int(part[base + 3 * stride]);
        const int pm[KNN] = { z * SEG + (int)(packed & 127u),
                              z * SEG + (int)((packed >> 7) & 127u),
                              z * SEG + (int)((packed >> 14) & 127u) };
#pragma unroll
        for (int k = 0; k < KNN; ++k) {
            const float dc = pd[k];
            const int   ic = pm[k];
            const bool c0 = dc < D0, c1 = dc < D1, c2 = dc < D2;
            const float oD0 = D0, oD1 = D1;
            const int   oI0 = I0, oI1 = I1;
            D0 = fminf(dc, D0);
            D1 = __builtin_amdgcn_fmed3f(dc, oD0, D1);
            D2 = __builtin_amdgcn_fmed3f(dc, oD1, D2);
            I0 = c0 ? ic : I0;
            I1 = c0 ? oI0 : (c1 ? ic : I1);
            I2 = c1 ? oI1 : (c2 ? ic : I2);
        }
    }

    const float* xb = xT + (size_t)b * NTOK * C_IN;
    float xg[KNN][C_IN];
    const int idx[KNN] = { I0, I1, I2 };
#pragma unroll
    for (int k = 0; k < KNN; ++k) {
        const float4* src = (const float4*)(xb + (size_t)idx[k] * C_IN);
#pragma unroll
        for (int j = 0; j < 4; ++j) {
            float4 t = src[j];
            xg[k][4 * j + 0] = t.x; xg[k][4 * j + 1] = t.y;
            xg[k][4 * j + 2] = t.z; xg[k][4 * j + 3] = t.w;
        }
    }

#pragma unroll
    for (int o = 0; o < C_OUT; ++o) {
        float acc = bias[o];
#pragma unroll
        for (int c = 0; c < C_IN; ++c) {
#pragma unroll
            for (int k = 0; k < KNN; ++k)
                acc = __fmaf_rn(W[(o * C_IN + c) * KNN + k], xg[k][c], acc);
        }
        out[((size_t)b * C_OUT + o) * NTOK + n] = acc;
    }
}

extern "C" void kernel_launch(void* const* d_in, const int* in_sizes, int n_in,
                              void* d_out, int out_size, void* d_ws, size_t ws_size,
                              hipStream_t stream) {
    const float* x    = (const float*)d_in[0];
    const float* W    = (const float*)d_in[1];
    const float* bias = (const float*)d_in[2];
    float* out = (float*)d_out;

    float* xT   = (float*)d_ws;                                  // 4 MB
    float* sq   = xT + (size_t)BATCH * NTOK * C_IN;              // 256 KB
    float* part = sq + (size_t)BATCH * NTOK;

    const size_t base_bytes = ((size_t)BATCH * NTOK * C_IN + (size_t)BATCH * NTOK) * 4;
    const size_t part32     = 4ull * 32 * BATCH * NTOK * 4;      // 33.6 MB

    dim3 grid1(NTOK / 256, BATCH);
    transpose_sq_kernel<<<grid1, 256, 0, stream>>>(x, xT, sq);

    if (ws_size >= base_bytes + part32) {
        // Z=32: SEG=64 -> 2048 blocks = 8 blocks/CU
        dim3 grid2(NTOK / NCHUNK, BATCH, 32);
        knn_partial_kernel<64><<<grid2, 256, 0, stream>>>(xT, sq, part);
        dim3 grid3(NTOK / 256, BATCH);
        merge_conv_kernel<64><<<grid3, 256, 0, stream>>>(xT, part, W, bias, out);
    } else {
        // Z=16: SEG=128 -> 1024 blocks (16.8 MB partials, fits known ws)
        dim3 grid2(NTOK / NCHUNK, BATCH, 16);
        knn_partial_kernel<128><<<grid2, 256, 0, stream>>>(xT, sq, part);
        dim3 grid3(NTOK / 256, BATCH);
        merge_conv_kernel<128><<<grid3, 256, 0, stream>>>(xT, part, W, bias, out);
    }
}

// Round 8
// 127.059 us; speedup vs baseline: 4.8472x; 4.8472x over previous
//
#include <hip/hip_runtime.h>
#include <float.h>
#include <limits.h>

#define BATCH 32
#define C_IN 16
#define C_OUT 32
#define NTOK 2048
#define KNN 3

using f32x4v = __attribute__((ext_vector_type(4))) float;
using bf16x8 = __attribute__((ext_vector_type(8))) short;

__device__ __forceinline__ unsigned short f2bf(float f) {
    unsigned u = __float_as_uint(f);
    unsigned r = u + 0x7fffu + ((u >> 16) & 1u);   // RNE
    return (unsigned short)(r >> 16);
}
__device__ __forceinline__ float bf2f(unsigned short h) {
    return __uint_as_float(((unsigned)h) << 16);
}

// Kernel 1: per (b,n): sq (exact ref recipe), xTf fp32 column, Am bf16 hi/lo split.
// Am row layout (64 B): [hi c0..c15 | lo c0..c15] -> serves both A-frags and B-frags.
__global__ void __launch_bounds__(256) prep_kernel(
    const float* __restrict__ x, float* __restrict__ xTf,
    float* __restrict__ sqf, uint4* __restrict__ Am)
{
    const int n = blockIdx.x * 256 + threadIdx.x;
    const int b = blockIdx.y;
    const float* xb = x + (size_t)b * C_IN * NTOK;

    float v[C_IN];
#pragma unroll
    for (int c = 0; c < C_IN; ++c) v[c] = xb[(size_t)c * NTOK + n];

    float acc = 0.0f;
#pragma unroll
    for (int c = 0; c < C_IN; ++c) acc = __fadd_rn(acc, __fmul_rn(v[c], v[c]));
    sqf[(size_t)b * NTOK + n] = acc;

    float4* dst = (float4*)(xTf + ((size_t)b * NTOK + n) * C_IN);
#pragma unroll
    for (int j = 0; j < 4; ++j)
        dst[j] = make_float4(v[4*j+0], v[4*j+1], v[4*j+2], v[4*j+3]);

    unsigned hw[8], lw[8];
#pragma unroll
    for (int j = 0; j < 8; ++j) {
        const unsigned short h0 = f2bf(v[2*j]),   h1 = f2bf(v[2*j+1]);
        const unsigned short l0 = f2bf(v[2*j]   - bf2f(h0));
        const unsigned short l1 = f2bf(v[2*j+1] - bf2f(h1));
        hw[j] = (unsigned)h0 | ((unsigned)h1 << 16);
        lw[j] = (unsigned)l0 | ((unsigned)l1 << 16);
    }
    uint4* am = Am + ((size_t)b * NTOK + n) * 4;
    am[0] = make_uint4(hw[0], hw[1], hw[2], hw[3]);
    am[1] = make_uint4(hw[4], hw[5], hw[6], hw[7]);
    am[2] = make_uint4(lw[0], lw[1], lw[2], lw[3]);
    am[3] = make_uint4(lw[4], lw[5], lw[6], lw[7]);
}

// Kernel 2: 1 wave per (b, 16-n tile). MFMA split-bf16 approx distances over all
// 2048 m; per-lane top-4 (disjoint 512-m subsets via C/D row layout); union of
// 4 lanes = 16 candidates/n; exact fp32 rescore (bitexact ref recipe); stable
// lexicographic top-3 select -> idxout.
__global__ void __launch_bounds__(64) knn_scan_kernel(
    const uint4* __restrict__ Am, const float* __restrict__ sqf,
    const float* __restrict__ xTf, int4* __restrict__ idxout)
{
    __shared__ float lds_cd[16][16];
    __shared__ int   lds_ci[16][16];
    __shared__ float lds_de[16][16];

    const int l    = threadIdx.x;
    const int col  = l & 15;
    const int quad = l >> 4;
    const int nt = blockIdx.x;
    const int b  = blockIdx.y;
    const int n  = nt * 16 + col;

    const char*  amb = (const char*)Am + ((size_t)b * NTOK * 64);
    const float* sqb = sqf + (size_t)b * NTOK;

    // B-frags (n-side): lane holds k-chunk quad*8..+7 of B[k][col];
    // B = [y_hi|y_hi] resp. [y_lo|y_lo] -> chunk (quad&1) of hi resp. lo.
    const int koffB = (quad & 1) * 16;
    const bf16x8 Bhi = *(const bf16x8*)(amb + (size_t)n * 64 + koffB);
    const bf16x8 Blo = *(const bf16x8*)(amb + (size_t)n * 64 + 32 + koffB);
    const float sqn = sqb[n];

    float d0 = FLT_MAX, d1 = FLT_MAX, d2 = FLT_MAX, d3 = FLT_MAX;
    int   i0 = 0, i1 = 0, i2 = 0, i3 = 0;
    const int moff = quad * 4;

#pragma unroll 2
    for (int t = 0; t < NTOK / 16; ++t) {
        // A-frag (m-side): lane row = col, k-chunk = quad -> Am row bytes quad*16
        const bf16x8 Af = *(const bf16x8*)(amb + (size_t)(t * 16 + col) * 64 + quad * 16);
        const float4 sq4 = *(const float4*)(sqb + t * 16 + moff);

        f32x4v acc = {0.0f, 0.0f, 0.0f, 0.0f};
        acc = __builtin_amdgcn_mfma_f32_16x16x32_bf16(Af, Bhi, acc, 0, 0, 0);
        acc = __builtin_amdgcn_mfma_f32_16x16x32_bf16(Af, Blo, acc, 0, 0, 0);

        const int mb = t * 16 + moff;
        const float sqa[4] = { sq4.x, sq4.y, sq4.z, sq4.w };
#pragma unroll
        for (int r = 0; r < 4; ++r) {
            const float d = __fadd_rn(__fmaf_rn(-2.0f, acc[r], sqn), sqa[r]);
            const int m = mb + r;
            // branchless top-4 insert on approx distance
            const bool c0 = d < d0, c1 = d < d1, c2 = d < d2, c3 = d < d3;
            const float od0 = d0, od1 = d1, od2 = d2;
            const int   oi0 = i0, oi1 = i1, oi2 = i2;
            d0 = fminf(d, d0);
            d1 = __builtin_amdgcn_fmed3f(d, od0, d1);
            d2 = __builtin_amdgcn_fmed3f(d, od1, d2);
            d3 = __builtin_amdgcn_fmed3f(d, od2, d3);
            i0 = c0 ? m : i0;
            i1 = c0 ? oi0 : (c1 ? m : i1);
            i2 = c1 ? oi1 : (c2 ? m : i2);
            i3 = c2 ? oi2 : (c3 ? m : i3);
        }
    }

    // dump 4 candidates per lane
    lds_cd[col][quad*4+0] = d0; lds_ci[col][quad*4+0] = i0;
    lds_cd[col][quad*4+1] = d1; lds_ci[col][quad*4+1] = i1;
    lds_cd[col][quad*4+2] = d2; lds_ci[col][quad*4+2] = i2;
    lds_cd[col][quad*4+3] = d3; lds_ci[col][quad*4+3] = i3;
    __syncthreads();

    // exact rescore: lane (col, quad) rescores candidates quad*4..+3 of n=col
    float xn[C_IN];
    {
        const float4* src = (const float4*)(xTf + ((size_t)b * NTOK + n) * C_IN);
#pragma unroll
        for (int j = 0; j < 4; ++j) {
            const float4 tq = src[j];
            xn[4*j+0] = tq.x; xn[4*j+1] = tq.y; xn[4*j+2] = tq.z; xn[4*j+3] = tq.w;
        }
    }
#pragma unroll
    for (int c = 0; c < 4; ++c) {
        const int cand = quad * 4 + c;
        const int mi = lds_ci[col][cand];
        const float4* xm4 = (const float4*)(xTf + ((size_t)b * NTOK + mi) * C_IN);
        const float4 a0 = xm4[0], a1 = xm4[1], a2 = xm4[2], a3 = xm4[3];
        float g = 0.0f;
        g = __fmaf_rn(xn[0],  a0.x, g); g = __fmaf_rn(xn[1],  a0.y, g);
        g = __fmaf_rn(xn[2],  a0.z, g); g = __fmaf_rn(xn[3],  a0.w, g);
        g = __fmaf_rn(xn[4],  a1.x, g); g = __fmaf_rn(xn[5],  a1.y, g);
        g = __fmaf_rn(xn[6],  a1.z, g); g = __fmaf_rn(xn[7],  a1.w, g);
        g = __fmaf_rn(xn[8],  a2.x, g); g = __fmaf_rn(xn[9],  a2.y, g);
        g = __fmaf_rn(xn[10], a2.z, g); g = __fmaf_rn(xn[11], a2.w, g);
        g = __fmaf_rn(xn[12], a3.x, g); g = __fmaf_rn(xn[13], a3.y, g);
        g = __fmaf_rn(xn[14], a3.z, g); g = __fmaf_rn(xn[15], a3.w, g);
        lds_de[col][cand] = __fadd_rn(__fmaf_rn(-2.0f, g, sqn), sqb[mi]);
    }
    __syncthreads();

    // stable top-3 over 16 exact (d, idx): lexicographic, matches jax top_k ties
    if (l < 16) {
        float D0 = FLT_MAX, D1 = FLT_MAX, D2 = FLT_MAX;
        int   I0 = INT_MAX, I1 = INT_MAX, I2 = INT_MAX;
#pragma unroll
        for (int c = 0; c < 16; ++c) {
            const float d = lds_de[l][c];
            const int  ix = lds_ci[l][c];
            const bool b0 = (d < D0) || (d == D0 && ix < I0);
            const bool b1 = (d < D1) || (d == D1 && ix < I1);
            const bool b2 = (d < D2) || (d == D2 && ix < I2);
            const float oD0 = D0, oD1 = D1;
            const int   oI0 = I0, oI1 = I1;
            D0 = b0 ? d : D0;           I0 = b0 ? ix : I0;
            D1 = b0 ? oD0 : (b1 ? d : D1);  I1 = b0 ? oI0 : (b1 ? ix : I1);
            D2 = b1 ? oD1 : (b2 ? d : D2);  I2 = b1 ? oI1 : (b2 ? ix : I2);
        }
        idxout[(size_t)b * NTOK + nt * 16 + l] = make_int4(I0, I1, I2, 0);
    }
}

// Kernel 3: gather 3 neighbor columns + conv epilogue (same recipe as rounds 1-7).
__global__ void __launch_bounds__(256) conv_kernel(
    const float* __restrict__ xTf, const int4* __restrict__ idxout,
    const float* __restrict__ W, const float* __restrict__ bias,
    float* __restrict__ out)
{
    const int n = blockIdx.x * 256 + threadIdx.x;
    const int b = blockIdx.y;
    const int4 id = idxout[(size_t)b * NTOK + n];
    const int idx[KNN] = { id.x, id.y, id.z };

    const float* xb = xTf + (size_t)b * NTOK * C_IN;
    float xg[KNN][C_IN];
#pragma unroll
    for (int k = 0; k < KNN; ++k) {
        const float4* src = (const float4*)(xb + (size_t)idx[k] * C_IN);
#pragma unroll
        for (int j = 0; j < 4; ++j) {
            const float4 t = src[j];
            xg[k][4*j+0] = t.x; xg[k][4*j+1] = t.y;
            xg[k][4*j+2] = t.z; xg[k][4*j+3] = t.w;
        }
    }

#pragma unroll
    for (int o = 0; o < C_OUT; ++o) {
        float acc = bias[o];
#pragma unroll
        for (int c = 0; c < C_IN; ++c) {
#pragma unroll
            for (int k = 0; k < KNN; ++k)
                acc = __fmaf_rn(W[(o * C_IN + c) * KNN + k], xg[k][c], acc);
        }
        out[((size_t)b * C_OUT + o) * NTOK + n] = acc;
    }
}

extern "C" void kernel_launch(void* const* d_in, const int* in_sizes, int n_in,
                              void* d_out, int out_size, void* d_ws, size_t ws_size,
                              hipStream_t stream) {
    const float* x    = (const float*)d_in[0];
    const float* W    = (const float*)d_in[1];
    const float* bias = (const float*)d_in[2];
    float* out = (float*)d_out;

    char* ws = (char*)d_ws;
    uint4* Am   = (uint4*)ws;                                   // 4 MB
    float* sqf  = (float*)(ws + (size_t)BATCH * NTOK * 64);     // 256 KB
    float* xTf  = (float*)(ws + (size_t)BATCH * NTOK * 64 + (size_t)BATCH * NTOK * 4); // 4 MB
    int4*  idxw = (int4*)(ws + (size_t)BATCH * NTOK * 64 + (size_t)BATCH * NTOK * 4
                             + (size_t)BATCH * NTOK * C_IN * 4); // 1 MB

    dim3 grid1(NTOK / 256, BATCH);
    prep_kernel<<<grid1, 256, 0, stream>>>(x, xTf, sqf, Am);

    dim3 grid2(NTOK / 16, BATCH);
    knn_scan_kernel<<<grid2, 64, 0, stream>>>(Am, sqf, xTf, idxw);

    dim3 grid3(NTOK / 256, BATCH);
    conv_kernel<<<grid3, 256, 0, stream>>>(xTf, idxw, W, bias, out);
}

// Round 9
// 121.739 us; speedup vs baseline: 5.0590x; 1.0437x over previous
//
#include <hip/hip_runtime.h>
#include <float.h>
#include <limits.h>

#define BATCH 32
#define C_IN 16
#define C_OUT 32
#define NTOK 2048
#define KNN 3
#define ZH 2                  // m-halves per n
#define MSEG (NTOK / ZH)      // 1024 m per scan wave

using f32x4v = __attribute__((ext_vector_type(4))) float;
using bf16x8 = __attribute__((ext_vector_type(8))) short;

__device__ __forceinline__ unsigned short f2bf(float f) {
    unsigned u = __float_as_uint(f);
    unsigned r = u + 0x7fffu + ((u >> 16) & 1u);   // RNE
    return (unsigned short)(r >> 16);
}
__device__ __forceinline__ float bf2f(unsigned short h) {
    return __uint_as_float(((unsigned)h) << 16);
}

// Kernel 1: per (b,n): sq (exact ref recipe), xTf fp32 column, Am bf16 hi/lo split.
// Am row layout (64 B): [hi c0..c15 | lo c0..c15] -> serves both A-frags and B-frags.
__global__ void __launch_bounds__(256) prep_kernel(
    const float* __restrict__ x, float* __restrict__ xTf,
    float* __restrict__ sqf, uint4* __restrict__ Am)
{
    const int n = blockIdx.x * 256 + threadIdx.x;
    const int b = blockIdx.y;
    const float* xb = x + (size_t)b * C_IN * NTOK;

    float v[C_IN];
#pragma unroll
    for (int c = 0; c < C_IN; ++c) v[c] = xb[(size_t)c * NTOK + n];

    float acc = 0.0f;
#pragma unroll
    for (int c = 0; c < C_IN; ++c) acc = __fadd_rn(acc, __fmul_rn(v[c], v[c]));
    sqf[(size_t)b * NTOK + n] = acc;

    float4* dst = (float4*)(xTf + ((size_t)b * NTOK + n) * C_IN);
#pragma unroll
    for (int j = 0; j < 4; ++j)
        dst[j] = make_float4(v[4*j+0], v[4*j+1], v[4*j+2], v[4*j+3]);

    unsigned hw[8], lw[8];
#pragma unroll
    for (int j = 0; j < 8; ++j) {
        const unsigned short h0 = f2bf(v[2*j]),   h1 = f2bf(v[2*j+1]);
        const unsigned short l0 = f2bf(v[2*j]   - bf2f(h0));
        const unsigned short l1 = f2bf(v[2*j+1] - bf2f(h1));
        hw[j] = (unsigned)h0 | ((unsigned)h1 << 16);
        lw[j] = (unsigned)l0 | ((unsigned)l1 << 16);
    }
    uint4* am = Am + ((size_t)b * NTOK + n) * 4;
    am[0] = make_uint4(hw[0], hw[1], hw[2], hw[3]);
    am[1] = make_uint4(hw[4], hw[5], hw[6], hw[7]);
    am[2] = make_uint4(lw[0], lw[1], lw[2], lw[3]);
    am[3] = make_uint4(lw[4], lw[5], lw[6], lw[7]);
}

// Kernel 2: 1 wave per (b, 16-n tile, m-half z). MFMA split-bf16 approx distances
// over MSEG m's; per-lane top-4 over disjoint 256-m subsets; union of 4 lanes =
// 16 candidates/n; exact fp32 rescore (bitexact ref recipe); stable top-3 of the
// half written as exact (d, global m) records.
__global__ void __launch_bounds__(64) knn_scan_kernel(
    const uint4* __restrict__ Am, const float* __restrict__ sqf,
    const float* __restrict__ xTf, float* __restrict__ pd, int* __restrict__ pi)
{
    __shared__ int   lds_ci[16][17];
    __shared__ float lds_de[16][17];

    const int l    = threadIdx.x;
    const int col  = l & 15;
    const int quad = l >> 4;
    const int nt = blockIdx.x;
    const int b  = blockIdx.y;
    const int z  = blockIdx.z;
    const int n  = nt * 16 + col;
    const int mbase = z * MSEG;

    const char*  amb = (const char*)Am + ((size_t)b * NTOK * 64);
    const float* sqb = sqf + (size_t)b * NTOK;

    // B-frags (n-side): lane holds k-chunk quad*8..+7 of B[k][col];
    // B = [y_hi|y_hi] resp. [y_lo|y_lo] -> chunk (quad&1) of hi resp. lo.
    const int koffB = (quad & 1) * 16;
    const bf16x8 Bhi = *(const bf16x8*)(amb + (size_t)n * 64 + koffB);
    const bf16x8 Blo = *(const bf16x8*)(amb + (size_t)n * 64 + 32 + koffB);

    float d0 = FLT_MAX, d1 = FLT_MAX, d2 = FLT_MAX, d3 = FLT_MAX;
    int   i0 = 0, i1 = 0, i2 = 0, i3 = 0;
    const int moff = quad * 4;

#pragma unroll 2
    for (int t = 0; t < MSEG / 16; ++t) {
        // A-frag (m-side): lane row = col, k-chunk = quad -> Am row bytes quad*16
        const bf16x8 Af = *(const bf16x8*)(amb + (size_t)(mbase + t * 16 + col) * 64 + quad * 16);
        const float4 sq4 = *(const float4*)(sqb + mbase + t * 16 + moff);

        f32x4v acc = {0.0f, 0.0f, 0.0f, 0.0f};
        acc = __builtin_amdgcn_mfma_f32_16x16x32_bf16(Af, Bhi, acc, 0, 0, 0);
        acc = __builtin_amdgcn_mfma_f32_16x16x32_bf16(Af, Blo, acc, 0, 0, 0);

        const int mb = mbase + t * 16 + moff;
        const float sqa[4] = { sq4.x, sq4.y, sq4.z, sq4.w };
#pragma unroll
        for (int r = 0; r < 4; ++r) {
            // ranking distance: sqn dropped (monotone per n) -> 1 fma
            const float d = __fmaf_rn(-2.0f, acc[r], sqa[r]);
            const int m = mb + r;
            // branchless top-4 insert on approx distance
            const bool c0 = d < d0, c1 = d < d1, c2 = d < d2, c3 = d < d3;
            const float od0 = d0, od1 = d1, od2 = d2;
            const int   oi0 = i0, oi1 = i1, oi2 = i2;
            d0 = fminf(d, d0);
            d1 = __builtin_amdgcn_fmed3f(d, od0, d1);
            d2 = __builtin_amdgcn_fmed3f(d, od1, d2);
            d3 = __builtin_amdgcn_fmed3f(d, od2, d3);
            i0 = c0 ? m : i0;
            i1 = c0 ? oi0 : (c1 ? m : i1);
            i2 = c1 ? oi1 : (c2 ? m : i2);
            i3 = c2 ? oi2 : (c3 ? m : i3);
        }
    }

    // dump 4 candidate indices per lane (global m)
    lds_ci[col][quad*4+0] = i0;
    lds_ci[col][quad*4+1] = i1;
    lds_ci[col][quad*4+2] = i2;
    lds_ci[col][quad*4+3] = i3;
    __syncthreads();

    // exact rescore: lane (col, quad) rescores candidates quad*4..+3 of n=col
    float xn[C_IN];
    {
        const float4* src = (const float4*)(xTf + ((size_t)b * NTOK + n) * C_IN);
#pragma unroll
        for (int j = 0; j < 4; ++j) {
            const float4 tq = src[j];
            xn[4*j+0] = tq.x; xn[4*j+1] = tq.y; xn[4*j+2] = tq.z; xn[4*j+3] = tq.w;
        }
    }
    const float sqn = sqb[n];
#pragma unroll
    for (int c = 0; c < 4; ++c) {
        const int cand = quad * 4 + c;
        const int mi = lds_ci[col][cand];
        const float4* xm4 = (const float4*)(xTf + ((size_t)b * NTOK + mi) * C_IN);
        const float4 a0 = xm4[0], a1 = xm4[1], a2 = xm4[2], a3 = xm4[3];
        float g = 0.0f;
        g = __fmaf_rn(xn[0],  a0.x, g); g = __fmaf_rn(xn[1],  a0.y, g);
        g = __fmaf_rn(xn[2],  a0.z, g); g = __fmaf_rn(xn[3],  a0.w, g);
        g = __fmaf_rn(xn[4],  a1.x, g); g = __fmaf_rn(xn[5],  a1.y, g);
        g = __fmaf_rn(xn[6],  a1.z, g); g = __fmaf_rn(xn[7],  a1.w, g);
        g = __fmaf_rn(xn[8],  a2.x, g); g = __fmaf_rn(xn[9],  a2.y, g);
        g = __fmaf_rn(xn[10], a2.z, g); g = __fmaf_rn(xn[11], a2.w, g);
        g = __fmaf_rn(xn[12], a3.x, g); g = __fmaf_rn(xn[13], a3.y, g);
        g = __fmaf_rn(xn[14], a3.z, g); g = __fmaf_rn(xn[15], a3.w, g);
        // exact (reference-rounded) distance
        lds_de[col][cand] = __fadd_rn(__fmaf_rn(-2.0f, g, sqn), sqb[mi]);
    }
    __syncthreads();

    // stable top-3 over 16 exact (d, idx): lexicographic, matches jax top_k ties
    if (l < 16) {
        float D0 = FLT_MAX, D1 = FLT_MAX, D2 = FLT_MAX;
        int   I0 = INT_MAX, I1 = INT_MAX, I2 = INT_MAX;
#pragma unroll
        for (int c = 0; c < 16; ++c) {
            const float d = lds_de[l][c];
            const int  ix = lds_ci[l][c];
            const bool b0 = (d < D0) || (d == D0 && ix < I0);
            const bool b1 = (d < D1) || (d == D1 && ix < I1);
            const bool b2 = (d < D2) || (d == D2 && ix < I2);
            const float oD0 = D0, oD1 = D1;
            const int   oI0 = I0, oI1 = I1;
            D0 = b0 ? d : D0;               I0 = b0 ? ix : I0;
            D1 = b0 ? oD0 : (b1 ? d : D1);  I1 = b0 ? oI0 : (b1 ? ix : I1);
            D2 = b1 ? oD1 : (b2 ? d : D2);  I2 = b1 ? oI1 : (b2 ? ix : I2);
        }
        // records: [((z*KNN + k)*BATCH + b)*NTOK + n]
        const size_t base = ((size_t)z * KNN * BATCH + b) * NTOK + nt * 16 + l;
        const size_t kstr = (size_t)BATCH * NTOK;
        pd[base + 0*kstr] = D0;  pi[base + 0*kstr] = I0;
        pd[base + 1*kstr] = D1;  pi[base + 1*kstr] = I1;
        pd[base + 2*kstr] = D2;  pi[base + 2*kstr] = I2;
    }
}

// Kernel 3: merge the 2 halves' exact top-3 (lexicographic on (d, m) == stable
// global top-3), gather 3 neighbor columns, conv epilogue.
__global__ void __launch_bounds__(256) merge_conv_kernel(
    const float* __restrict__ xTf, const float* __restrict__ pd,
    const int* __restrict__ pi, const float* __restrict__ W,
    const float* __restrict__ bias, float* __restrict__ out)
{
    const int n = blockIdx.x * 256 + threadIdx.x;
    const int b = blockIdx.y;

    float D0 = FLT_MAX, D1 = FLT_MAX, D2 = FLT_MAX;
    int   I0 = INT_MAX, I1 = INT_MAX, I2 = INT_MAX;
    const size_t kstr = (size_t)BATCH * NTOK;
#pragma unroll
    for (int z = 0; z < ZH; ++z) {
        const size_t base = ((size_t)z * KNN * BATCH + b) * NTOK + n;
#pragma unroll
        for (int k = 0; k < KNN; ++k) {
            const float d = pd[base + (size_t)k * kstr];
            const int  ix = pi[base + (size_t)k * kstr];
            const bool b0 = (d < D0) || (d == D0 && ix < I0);
            const bool b1 = (d < D1) || (d == D1 && ix < I1);
            const bool b2 = (d < D2) || (d == D2 && ix < I2);
            const float oD0 = D0, oD1 = D1;
            const int   oI0 = I0, oI1 = I1;
            D0 = b0 ? d : D0;               I0 = b0 ? ix : I0;
            D1 = b0 ? oD0 : (b1 ? d : D1);  I1 = b0 ? oI0 : (b1 ? ix : I1);
            D2 = b1 ? oD1 : (b2 ? d : D2);  I2 = b1 ? oI1 : (b2 ? ix : I2);
        }
    }

    const float* xb = xTf + (size_t)b * NTOK * C_IN;
    float xg[KNN][C_IN];
    const int idx[KNN] = { I0, I1, I2 };
#pragma unroll
    for (int k = 0; k < KNN; ++k) {
        const float4* src = (const float4*)(xb + (size_t)idx[k] * C_IN);
#pragma unroll
        for (int j = 0; j < 4; ++j) {
            const float4 t = src[j];
            xg[k][4*j+0] = t.x; xg[k][4*j+1] = t.y;
            xg[k][4*j+2] = t.z; xg[k][4*j+3] = t.w;
        }
    }

#pragma unroll
    for (int o = 0; o < C_OUT; ++o) {
        float acc = bias[o];
#pragma unroll
        for (int c = 0; c < C_IN; ++c) {
#pragma unroll
            for (int k = 0; k < KNN; ++k)
                acc = __fmaf_rn(W[(o * C_IN + c) * KNN + k], xg[k][c], acc);
        }
        out[((size_t)b * C_OUT + o) * NTOK + n] = acc;
    }
}

extern "C" void kernel_launch(void* const* d_in, const int* in_sizes, int n_in,
                              void* d_out, int out_size, void* d_ws, size_t ws_size,
                              hipStream_t stream) {
    const float* x    = (const float*)d_in[0];
    const float* W    = (const float*)d_in[1];
    const float* bias = (const float*)d_in[2];
    float* out = (float*)d_out;

    char* ws = (char*)d_ws;
    const size_t BN = (size_t)BATCH * NTOK;
    uint4* Am  = (uint4*)ws;                       // 4 MB
    float* sqf = (float*)(ws + BN * 64);           // 256 KB
    float* xTf = (float*)(ws + BN * 68);           // 4 MB
    float* pd  = (float*)(ws + BN * 68 + BN * 64); // ZH*KNN*BN*4 = 1.5 MB
    int*   pi  = (int*)  (ws + BN * 68 + BN * 64 + (size_t)ZH * KNN * BN * 4);

    dim3 grid1(NTOK / 256, BATCH);
    prep_kernel<<<grid1, 256, 0, stream>>>(x, xTf, sqf, Am);

    dim3 grid2(NTOK / 16, BATCH, ZH);
    knn_scan_kernel<<<grid2, 64, 0, stream>>>(Am, sqf, xTf, pd, pi);

    dim3 grid3(NTOK / 256, BATCH);
    merge_conv_kernel<<<grid3, 256, 0, stream>>>(xTf, pd, pi, W, bias, out);
}

// Round 10
// 110.309 us; speedup vs baseline: 5.5832x; 1.1036x over previous
//
#include <hip/hip_runtime.h>
#include <float.h>
#include <limits.h>

#define BATCH 32
#define C_IN 16
#define C_OUT 32
#define NTOK 2048
#define KNN 3
#define ZH 2                  // m-halves per n
#define MSEG (NTOK / ZH)      // 1024 m per scan wave
#define WPB 4                 // waves per block (independent n-tiles)

using f32x4v = __attribute__((ext_vector_type(4))) float;
using bf16x8 = __attribute__((ext_vector_type(8))) short;

__device__ __forceinline__ unsigned short f2bf(float f) {
    unsigned u = __float_as_uint(f);
    unsigned r = u + 0x7fffu + ((u >> 16) & 1u);   // RNE
    return (unsigned short)(r >> 16);
}
__device__ __forceinline__ float bf2f(unsigned short h) {
    return __uint_as_float(((unsigned)h) << 16);
}
__device__ __forceinline__ unsigned umin2(unsigned a, unsigned b) { return a < b ? a : b; }
__device__ __forceinline__ unsigned umax2(unsigned a, unsigned b) { return a > b ? a : b; }

// Kernel 1: per (b,n): sq (exact ref recipe), xTf fp32 column, Am bf16 hi/lo split.
// Am row layout (64 B): [hi c0..c15 | lo c0..c15] -> serves both A-frags and B-frags.
__global__ void __launch_bounds__(256) prep_kernel(
    const float* __restrict__ x, float* __restrict__ xTf,
    float* __restrict__ sqf, uint4* __restrict__ Am)
{
    const int n = blockIdx.x * 256 + threadIdx.x;
    const int b = blockIdx.y;
    const float* xb = x + (size_t)b * C_IN * NTOK;

    float v[C_IN];
#pragma unroll
    for (int c = 0; c < C_IN; ++c) v[c] = xb[(size_t)c * NTOK + n];

    float acc = 0.0f;
#pragma unroll
    for (int c = 0; c < C_IN; ++c) acc = __fadd_rn(acc, __fmul_rn(v[c], v[c]));
    sqf[(size_t)b * NTOK + n] = acc;

    float4* dst = (float4*)(xTf + ((size_t)b * NTOK + n) * C_IN);
#pragma unroll
    for (int j = 0; j < 4; ++j)
        dst[j] = make_float4(v[4*j+0], v[4*j+1], v[4*j+2], v[4*j+3]);

    unsigned hw[8], lw[8];
#pragma unroll
    for (int j = 0; j < 8; ++j) {
        const unsigned short h0 = f2bf(v[2*j]),   h1 = f2bf(v[2*j+1]);
        const unsigned short l0 = f2bf(v[2*j]   - bf2f(h0));
        const unsigned short l1 = f2bf(v[2*j+1] - bf2f(h1));
        hw[j] = (unsigned)h0 | ((unsigned)h1 << 16);
        lw[j] = (unsigned)l0 | ((unsigned)l1 << 16);
    }
    uint4* am = Am + ((size_t)b * NTOK + n) * 4;
    am[0] = make_uint4(hw[0], hw[1], hw[2], hw[3]);
    am[1] = make_uint4(hw[4], hw[5], hw[6], hw[7]);
    am[2] = make_uint4(lw[0], lw[1], lw[2], lw[3]);
    am[3] = make_uint4(lw[4], lw[5], lw[6], lw[7]);
}

// Kernel 2: 256-thr block = 4 independent waves, wave w owns n-tile blockIdx.x*4+w,
// m-half z. MFMA split-bf16 approx distances; per-lane top-4 as packed sortable
// keys (quantized d in high 21 bits, global m in low 11); union of 4 lanes = 16
// candidates/n; exact fp32 rescore (bitexact ref recipe); stable top-3 of the half.
__global__ void __launch_bounds__(256) knn_scan_kernel(
    const uint4* __restrict__ Am, const float* __restrict__ sqf,
    const float* __restrict__ xTf, float* __restrict__ pd, int* __restrict__ pi)
{
    __shared__ int   lds_ci[WPB][16][17];
    __shared__ float lds_de[WPB][16][17];

    const int tid  = threadIdx.x;
    const int w    = tid >> 6;
    const int l    = tid & 63;
    const int col  = l & 15;
    const int quad = l >> 4;
    const int nt = blockIdx.x * WPB + w;
    const int b  = blockIdx.y;
    const int z  = blockIdx.z;
    const int n  = nt * 16 + col;
    const int mbase = z * MSEG;

    const char*  amb = (const char*)Am + ((size_t)b * NTOK * 64);
    const float* sqb = sqf + (size_t)b * NTOK;

    // B-frags (n-side): lane holds k-chunk quad*8..+7 of B[k][col];
    // B = [y_hi|y_hi] resp. [y_lo|y_lo] -> chunk (quad&1) of hi resp. lo.
    const int koffB = (quad & 1) * 16;
    const bf16x8 Bhi = *(const bf16x8*)(amb + (size_t)n * 64 + koffB);
    const bf16x8 Blo = *(const bf16x8*)(amb + (size_t)n * 64 + 32 + koffB);

    unsigned k0 = ~0u, k1 = ~0u, k2 = ~0u, k3 = ~0u;
    const int moff = quad * 4;

#pragma unroll 2
    for (int t = 0; t < MSEG / 16; ++t) {
        // A-frag (m-side): lane row = col, k-chunk = quad -> Am row bytes quad*16
        const bf16x8 Af = *(const bf16x8*)(amb + (size_t)(mbase + t * 16 + col) * 64 + quad * 16);
        const float4 sq4 = *(const float4*)(sqb + mbase + t * 16 + moff);

        f32x4v acc = {0.0f, 0.0f, 0.0f, 0.0f};
        acc = __builtin_amdgcn_mfma_f32_16x16x32_bf16(Af, Bhi, acc, 0, 0, 0);
        acc = __builtin_amdgcn_mfma_f32_16x16x32_bf16(Af, Blo, acc, 0, 0, 0);

        const int mb = mbase + t * 16 + moff;
        const float sqa[4] = { sq4.x, sq4.y, sq4.z, sq4.w };
#pragma unroll
        for (int r = 0; r < 4; ++r) {
            // ranking distance: sqn dropped (monotone per n)
            const float d = __fmaf_rn(-2.0f, acc[r], sqa[r]);
            // sortable-uint transform (ascending) + pack global m into low 11 bits
            unsigned u = __float_as_uint(d);
            u ^= (unsigned)((int)u >> 31) | 0x80000000u;
            const unsigned key = (u & 0xFFFFF800u) | (unsigned)(mb + r);
            // top-4 insert, pure min/max chain (no index bookkeeping)
            const unsigned ok0 = k0, ok1 = k1, ok2 = k2;
            k0 = umin2(key, k0);
            k1 = umin2(umax2(key, ok0), k1);
            k2 = umin2(umax2(key, ok1), k2);
            k3 = umin2(umax2(key, ok2), k3);
        }
    }

    // dump 4 candidate indices per lane (decode global m from key)
    lds_ci[w][col][quad*4+0] = (int)(k0 & 2047u);
    lds_ci[w][col][quad*4+1] = (int)(k1 & 2047u);
    lds_ci[w][col][quad*4+2] = (int)(k2 & 2047u);
    lds_ci[w][col][quad*4+3] = (int)(k3 & 2047u);
    __syncthreads();

    // exact rescore: lane (col, quad) rescores candidates quad*4..+3 of n=col
    float xn[C_IN];
    {
        const float4* src = (const float4*)(xTf + ((size_t)b * NTOK + n) * C_IN);
#pragma unroll
        for (int j = 0; j < 4; ++j) {
            const float4 tq = src[j];
            xn[4*j+0] = tq.x; xn[4*j+1] = tq.y; xn[4*j+2] = tq.z; xn[4*j+3] = tq.w;
        }
    }
    const float sqn = sqb[n];
#pragma unroll
    for (int c = 0; c < 4; ++c) {
        const int cand = quad * 4 + c;
        const int mi = lds_ci[w][col][cand];
        const float4* xm4 = (const float4*)(xTf + ((size_t)b * NTOK + mi) * C_IN);
        const float4 a0 = xm4[0], a1 = xm4[1], a2 = xm4[2], a3 = xm4[3];
        float g = 0.0f;
        g = __fmaf_rn(xn[0],  a0.x, g); g = __fmaf_rn(xn[1],  a0.y, g);
        g = __fmaf_rn(xn[2],  a0.z, g); g = __fmaf_rn(xn[3],  a0.w, g);
        g = __fmaf_rn(xn[4],  a1.x, g); g = __fmaf_rn(xn[5],  a1.y, g);
        g = __fmaf_rn(xn[6],  a1.z, g); g = __fmaf_rn(xn[7],  a1.w, g);
        g = __fmaf_rn(xn[8],  a2.x, g); g = __fmaf_rn(xn[9],  a2.y, g);
        g = __fmaf_rn(xn[10], a2.z, g); g = __fmaf_rn(xn[11], a2.w, g);
        g = __fmaf_rn(xn[12], a3.x, g); g = __fmaf_rn(xn[13], a3.y, g);
        g = __fmaf_rn(xn[14], a3.z, g); g = __fmaf_rn(xn[15], a3.w, g);
        // exact (reference-rounded) distance
        lds_de[w][col][cand] = __fadd_rn(__fmaf_rn(-2.0f, g, sqn), sqb[mi]);
    }
    __syncthreads();

    // stable top-3 over 16 exact (d, idx): lexicographic, matches jax top_k ties
    if (l < 16) {
        float D0 = FLT_MAX, D1 = FLT_MAX, D2 = FLT_MAX;
        int   I0 = INT_MAX, I1 = INT_MAX, I2 = INT_MAX;
#pragma unroll
        for (int c = 0; c < 16; ++c) {
            const float d = lds_de[w][l][c];
            const int  ix = lds_ci[w][l][c];
            const bool b0 = (d < D0) || (d == D0 && ix < I0);
            const bool b1 = (d < D1) || (d == D1 && ix < I1);
            const bool b2 = (d < D2) || (d == D2 && ix < I2);
            const float oD0 = D0, oD1 = D1;
            const int   oI0 = I0, oI1 = I1;
            D0 = b0 ? d : D0;               I0 = b0 ? ix : I0;
            D1 = b0 ? oD0 : (b1 ? d : D1);  I1 = b0 ? oI0 : (b1 ? ix : I1);
            D2 = b1 ? oD1 : (b2 ? d : D2);  I2 = b1 ? oI1 : (b2 ? ix : I2);
        }
        // records: [((z*KNN + k)*BATCH + b)*NTOK + n]
        const size_t base = ((size_t)z * KNN * BATCH + b) * NTOK + nt * 16 + l;
        const size_t kstr = (size_t)BATCH * NTOK;
        pd[base + 0*kstr] = D0;  pi[base + 0*kstr] = I0;
        pd[base + 1*kstr] = D1;  pi[base + 1*kstr] = I1;
        pd[base + 2*kstr] = D2;  pi[base + 2*kstr] = I2;
    }
}

// Kernel 3: merge the 2 halves' exact top-3 (lexicographic on (d, m) == stable
// global top-3), gather 3 neighbor columns, conv epilogue.
__global__ void __launch_bounds__(256) merge_conv_kernel(
    const float* __restrict__ xTf, const float* __restrict__ pd,
    const int* __restrict__ pi, const float* __restrict__ W,
    const float* __restrict__ bias, float* __restrict__ out)
{
    const int n = blockIdx.x * 256 + threadIdx.x;
    const int b = blockIdx.y;

    float D0 = FLT_MAX, D1 = FLT_MAX, D2 = FLT_MAX;
    int   I0 = INT_MAX, I1 = INT_MAX, I2 = INT_MAX;
    const size_t kstr = (size_t)BATCH * NTOK;
#pragma unroll
    for (int z = 0; z < ZH; ++z) {
        const size_t base = ((size_t)z * KNN * BATCH + b) * NTOK + n;
#pragma unroll
        for (int k = 0; k < KNN; ++k) {
            const float d = pd[base + (size_t)k * kstr];
            const int  ix = pi[base + (size_t)k * kstr];
            const bool b0 = (d < D0) || (d == D0 && ix < I0);
            const bool b1 = (d < D1) || (d == D1 && ix < I1);
            const bool b2 = (d < D2) || (d == D2 && ix < I2);
            const float oD0 = D0, oD1 = D1;
            const int   oI0 = I0, oI1 = I1;
            D0 = b0 ? d : D0;               I0 = b0 ? ix : I0;
            D1 = b0 ? oD0 : (b1 ? d : D1);  I1 = b0 ? oI0 : (b1 ? ix : I1);
            D2 = b1 ? oD1 : (b2 ? d : D2);  I2 = b1 ? oI1 : (b2 ? ix : I2);
        }
    }

    const float* xb = xTf + (size_t)b * NTOK * C_IN;
    float xg[KNN][C_IN];
    const int idx[KNN] = { I0, I1, I2 };
#pragma unroll
    for (int k = 0; k < KNN; ++k) {
        const float4* src = (const float4*)(xb + (size_t)idx[k] * C_IN);
#pragma unroll
        for (int j = 0; j < 4; ++j) {
            const float4 t = src[j];
            xg[k][4*j+0] = t.x; xg[k][4*j+1] = t.y;
            xg[k][4*j+2] = t.z; xg[k][4*j+3] = t.w;
        }
    }

#pragma unroll
    for (int o = 0; o < C_OUT; ++o) {
        float acc = bias[o];
#pragma unroll
        for (int c = 0; c < C_IN; ++c) {
#pragma unroll
            for (int k = 0; k < KNN; ++k)
                acc = __fmaf_rn(W[(o * C_IN + c) * KNN + k], xg[k][c], acc);
        }
        out[((size_t)b * C_OUT + o) * NTOK + n] = acc;
    }
}

extern "C" void kernel_launch(void* const* d_in, const int* in_sizes, int n_in,
                              void* d_out, int out_size, void* d_ws, size_t ws_size,
                              hipStream_t stream) {
    const float* x    = (const float*)d_in[0];
    const float* W    = (const float*)d_in[1];
    const float* bias = (const float*)d_in[2];
    float* out = (float*)d_out;

    char* ws = (char*)d_ws;
    const size_t BN = (size_t)BATCH * NTOK;
    uint4* Am  = (uint4*)ws;                       // 4 MB
    float* sqf = (float*)(ws + BN * 64);           // 256 KB
    float* xTf = (float*)(ws + BN * 68);           // 4 MB
    float* pd  = (float*)(ws + BN * 68 + BN * 64); // ZH*KNN*BN*4 = 1.5 MB
    int*   pi  = (int*)  (ws + BN * 68 + BN * 64 + (size_t)ZH * KNN * BN * 4);

    dim3 grid1(NTOK / 256, BATCH);
    prep_kernel<<<grid1, 256, 0, stream>>>(x, xTf, sqf, Am);

    dim3 grid2(NTOK / (16 * WPB), BATCH, ZH);
    knn_scan_kernel<<<grid2, 256, 0, stream>>>(Am, sqf, xTf, pd, pi);

    dim3 grid3(NTOK / 256, BATCH);
    merge_conv_kernel<<<grid3, 256, 0, stream>>>(xTf, pd, pi, W, bias, out);
}